// Round 1
// baseline (43.507 us; speedup 1.0000x reference)
//
#include <hip/hip_runtime.h>

#define NB   4
#define CIN  32
#define HH   56
#define WW   56
#define GIN  8
#define GOUT 8
#define LIN  4
#define LOUT 8
#define KK   9
#define HW   (HH * WW)        // 3136
#define PIXTOT (NB * HW)      // 12544
#define PPB  32               // pixels per block (256 thr = 32 pix * 8 g)
#define WSLICE (GIN * KK * LIN * LOUT)  // 2304 floats per c
#define WS_G 292              // padded per-g LDS stride (288 + 4) -> conflict-free float4 reads

__global__ __launch_bounds__(256) void caps_routing_kernel(
    const float* __restrict__ x, const float* __restrict__ wt,
    float* __restrict__ out)
{
    __shared__ float ws[GIN * WS_G];   // 9344 B

    const int tid = threadIdx.x;
    const int c = blockIdx.y;

    // stage this c's weight slice: [g][k][l][m] (288 floats per g, padded to 292)
    const float* wsrc = wt + c * WSLICE;
    for (int i = tid; i < WSLICE; i += 256) {
        const int g = i / 288;
        const int r = i - g * 288;
        ws[g * WS_G + r] = wsrc[i];
    }
    __syncthreads();

    const int g  = tid & 7;
    const int pl = tid >> 3;
    const int pix = blockIdx.x * PPB + pl;   // 392*32 == 12544 exactly, no bounds check
    const int n = pix / HW;
    const int p = pix - n * HW;
    const int h = p / WW;
    const int w = p - h * WW;

    // gather the 3x3 x LIN input patch for capsule-group g (zero padding at borders)
    float xv[KK][LIN];
    const float* xb = x + (n * CIN + g * LIN) * HW;
    #pragma unroll
    for (int ki = 0; ki < 3; ++ki) {
        const int hh = h - 1 + ki;
        const bool hok = (unsigned)hh < (unsigned)HH;
        #pragma unroll
        for (int kj = 0; kj < 3; ++kj) {
            const int wp = w - 1 + kj;
            const bool ok = hok && ((unsigned)wp < (unsigned)WW);
            const int off = hh * WW + wp;
            #pragma unroll
            for (int l = 0; l < LIN; ++l)
                xv[ki * 3 + kj][l] = ok ? xb[l * HW + off] : 0.0f;
        }
    }

    // priors[k][m] = sum_l xv[k][l] * W[c,g,k,l,m]
    float pr[KK][LOUT];
    const float* wg = &ws[g * WS_G];
    #pragma unroll
    for (int k = 0; k < KK; ++k) {
        float4 a0 = make_float4(0.f, 0.f, 0.f, 0.f);
        float4 a1 = make_float4(0.f, 0.f, 0.f, 0.f);
        #pragma unroll
        for (int l = 0; l < LIN; ++l) {
            const float4* wp4 = reinterpret_cast<const float4*>(wg + k * 32 + l * 8);
            const float xs = xv[k][l];
            const float4 w0 = wp4[0];
            const float4 w1 = wp4[1];
            a0.x = fmaf(xs, w0.x, a0.x); a0.y = fmaf(xs, w0.y, a0.y);
            a0.z = fmaf(xs, w0.z, a0.z); a0.w = fmaf(xs, w0.w, a0.w);
            a1.x = fmaf(xs, w1.x, a1.x); a1.y = fmaf(xs, w1.y, a1.y);
            a1.z = fmaf(xs, w1.z, a1.z); a1.w = fmaf(xs, w1.w, a1.w);
        }
        pr[k][0] = a0.x; pr[k][1] = a0.y; pr[k][2] = a0.z; pr[k][3] = a0.w;
        pr[k][4] = a1.x; pr[k][5] = a1.y; pr[k][6] = a1.z; pr[k][7] = a1.w;
    }

    // dynamic routing, ITERS = 3, fully in registers
    float logits[KK];
    #pragma unroll
    for (int k = 0; k < KK; ++k) logits[k] = 0.0f;

    float v[LOUT];
    #pragma unroll
    for (int it = 0; it < 3; ++it) {
        float probs[KK];
        if (it == 0) {
            #pragma unroll
            for (int k = 0; k < KK; ++k) probs[k] = 1.0f / 9.0f;  // softmax(0)
        } else {
            float mx = logits[0];
            #pragma unroll
            for (int k = 1; k < KK; ++k) mx = fmaxf(mx, logits[k]);
            float sum = 0.0f;
            #pragma unroll
            for (int k = 0; k < KK; ++k) { probs[k] = __expf(logits[k] - mx); sum += probs[k]; }
            const float inv = 1.0f / sum;
            #pragma unroll
            for (int k = 0; k < KK; ++k) probs[k] *= inv;
        }

        // per-lane partial s[m] over k, then reduce over the 8 g-lanes
        float s[LOUT];
        #pragma unroll
        for (int m = 0; m < LOUT; ++m) {
            float acc = 0.0f;
            #pragma unroll
            for (int k = 0; k < KK; ++k) acc = fmaf(probs[k], pr[k][m], acc);
            s[m] = acc;
        }
        #pragma unroll
        for (int off = 1; off < 8; off <<= 1) {
            #pragma unroll
            for (int m = 0; m < LOUT; ++m)
                s[m] += __shfl_xor(s[m], off, 64);
        }

        // squash: v = (|s| / (1 + |s|^2)) * s
        float n2 = 0.0f;
        #pragma unroll
        for (int m = 0; m < LOUT; ++m) n2 = fmaf(s[m], s[m], n2);
        const float f = sqrtf(n2) / (1.0f + n2);
        #pragma unroll
        for (int m = 0; m < LOUT; ++m) v[m] = f * s[m];

        if (it != 2) {
            #pragma unroll
            for (int k = 0; k < KK; ++k) {
                float d = 0.0f;
                #pragma unroll
                for (int m = 0; m < LOUT; ++m) d = fmaf(pr[k][m], v[m], d);
                logits[k] += d;
            }
        }
    }

    // lane (pl, g) writes output component m = g (static-index select, no scratch)
    float outv = v[0];
    #pragma unroll
    for (int m = 1; m < LOUT; ++m) if (g == m) outv = v[m];
    out[(n * GOUT * LOUT + c * LOUT + g) * HW + p] = outv;
}

extern "C" void kernel_launch(void* const* d_in, const int* in_sizes, int n_in,
                              void* d_out, int out_size, void* d_ws, size_t ws_size,
                              hipStream_t stream) {
    const float* x  = (const float*)d_in[0];
    const float* wt = (const float*)d_in[1];
    float* out = (float*)d_out;
    dim3 grid(PIXTOT / PPB, GOUT);   // 392 x 8
    caps_routing_kernel<<<grid, dim3(256), 0, stream>>>(x, wt, out);
}